// Round 10
// baseline (364.698 us; speedup 1.0000x reference)
//
#include <hip/hip_runtime.h>

typedef unsigned short u16;
typedef unsigned int   u32;
typedef unsigned long long u64;

typedef __attribute__((ext_vector_type(8))) short  bf16x8;
typedef __attribute__((ext_vector_type(16))) float f32x16;

#define SC2 0.1803368801111243f    // SCALE(0.125) * log2(e)
#define CS2 11.541560327111707f    // 8 * log2(e)  (fixed softmax shift)

__device__ __forceinline__ float bf2f(u16 h) { return __uint_as_float(((u32)h) << 16); }
__device__ __forceinline__ u16 f2bf(float f) {
  u32 u = __float_as_uint(f);
  return (u16)((u + 0x7FFFu + ((u >> 16) & 1u)) >> 16);   // RNE
}
__device__ __forceinline__ float gelu_f(float x) {
  return 0.5f * x * (1.0f + erff(x * 0.70710678118654752440f));
}
// async global->LDS DMA, 16B/lane (lane i -> ldsbase + i*16)
__device__ __forceinline__ void dma16(const u16* g, u16* l) {
  __builtin_amdgcn_global_load_lds(
      (const __attribute__((address_space(1))) u32*)g,
      (__attribute__((address_space(3))) u32*)l, 16, 0, 0);
}
// 2xf32 -> packed bf16 (RNE), 1 VALU op (no builtin on gfx950)
__device__ __forceinline__ u32 cvtpk(float lo, float hi) {
  u32 r;
  asm("v_cvt_pk_bf16_f32 %0, %1, %2" : "=v"(r) : "v"(lo), "v"(hi));
  return r;
}

// ---------------------------------------------------------------------------
// dtype detection (flag=1 -> fp32 inputs; HW-confirmed fp32)
// ---------------------------------------------------------------------------
__global__ void detect_dtype(const u16* __restrict__ X, u32* __restrict__ flag) {
  int lane = threadIdx.x;
  int bad = 0;
  #pragma unroll
  for (int i = 0; i < 8; ++i) {
    u16 v = X[i * 64 + lane];
    int e = (v >> 7) & 0xFF;
    if (e >= 0x88) bad++;
  }
  #pragma unroll
  for (int o = 1; o < 64; o <<= 1) bad += __shfl_xor(bad, o);
  if (lane == 0) *flag = (bad > 16) ? 1u : 0u;
}

__global__ __launch_bounds__(256) void fill_diag(u32* __restrict__ out, float base,
                                                 const u32* __restrict__ flag) {
  float v = base + (*flag ? 4000.0f : 0.0f);
  u16 h = f2bf(v);
  out[blockIdx.x * 256 + threadIdx.x] = (u32)h | ((u32)h << 16);
}

// ---------------------------------------------------------------------------
// Fused prep (round 9, unchanged): convX | convE | FWT build | vec10 |
// inc_tiles_edge.
//   blocks [0,2048)      : X -> XB bf16
//   blocks [2048,3072)   : E -> EB
//   blocks [3072,4096)   : 8 weights -> FWT in MFMA-B-FRAGMENT order:
//                          FWT[z][n32:16][kk:8][ks:4][lane:64][e:8]
//                          = W[k][n], k=kk*64+(ks*2+(l>>5))*8+e, n=n32*32+(l&31)
//   block  4096          : 10 bias vecs -> VEC
//   blocks [4097,8193)   : edge mask tiles -> ETIL0/ETIL1
// ---------------------------------------------------------------------------
__global__ __launch_bounds__(256) void prep_all(
    const void* __restrict__ Xsrc, const void* __restrict__ Esrc,
    const int* __restrict__ inc,
    const void* w0, const void* w1, const void* w2, const void* w3,
    const void* w4, const void* w5, const void* w6, const void* w7,
    const void* p0, const void* p1, const void* p2, const void* p3, const void* p4,
    const void* p5, const void* p6, const void* p7, const void* p8, const void* p9,
    u16* __restrict__ XB, u16* __restrict__ EB, u16* __restrict__ FWT,
    u16* __restrict__ VEC, u16* __restrict__ T0, u16* __restrict__ T1,
    const u32* __restrict__ flag) {
  int bi = blockIdx.x;
  int t = threadIdx.x;
  int fl = (int)(*flag);

  if (bi < 3072) {            // conv X (bi<2048) / conv E
    const void* src = bi < 2048 ? Xsrc : Esrc;
    u16* dst = bi < 2048 ? XB : EB;
    int base = bi < 2048 ? bi : bi - 2048;
    int i = (base * 256 + t) * 8;
    if (fl) {
      const float* s = (const float*)src + i;
      float4 a = *(const float4*)s;
      float4 b = *(const float4*)(s + 4);
      uint4 o;
      o.x = (u32)f2bf(a.x) | ((u32)f2bf(a.y) << 16);
      o.y = (u32)f2bf(a.z) | ((u32)f2bf(a.w) << 16);
      o.z = (u32)f2bf(b.x) | ((u32)f2bf(b.y) << 16);
      o.w = (u32)f2bf(b.z) | ((u32)f2bf(b.w) << 16);
      *(uint4*)(dst + i) = o;
    } else {
      *(uint4*)(dst + i) = *(const uint4*)((const u16*)src + i);
    }
  } else if (bi < 4096) {     // weight -> fragment-ordered FWT
    const void* wsrc[8] = {w0, w1, w2, w3, w4, w5, w6, w7};
    int r = bi - 3072;        // [0,1024): z[3] n32[4] kk[3]
    int z = r >> 7;
    int n32 = (r >> 3) & 15;
    int kk = r & 7;
    const void* W = wsrc[z];
    int ks = t >> 6, l = t & 63;
    int nl = l & 31, h32 = l >> 5;
    int n = n32 * 32 + nl;
    int k0 = kk * 64 + (ks * 2 + h32) * 8;
    u16 o[8];
    if (fl) {
      #pragma unroll
      for (int e = 0; e < 8; ++e)
        o[e] = f2bf(((const float*)W)[(size_t)(k0 + e) * 512 + n]);
    } else {
      #pragma unroll
      for (int e = 0; e < 8; ++e)
        o[e] = ((const u16*)W)[(size_t)(k0 + e) * 512 + n];
    }
    uint4 ov;
    ov.x = (u32)o[0] | ((u32)o[1] << 16);
    ov.y = (u32)o[2] | ((u32)o[3] << 16);
    ov.z = (u32)o[4] | ((u32)o[5] << 16);
    ov.w = (u32)o[6] | ((u32)o[7] << 16);
    size_t slab = ((size_t)n32 * 8 + kk) * 4 + ks;
    *(uint4*)(FWT + (size_t)z * 262144 + slab * 512 + l * 8) = ov;
  } else if (bi == 4096) {    // bias vectors
    const void* ps[10] = {p0, p1, p2, p3, p4, p5, p6, p7, p8, p9};
    for (int idx = t; idx < 5120; idx += 256) {
      int slot = idx >> 9, off = idx & 511;
      u16 v;
      if (fl) v = f2bf(((const float*)ps[slot])[off]);
      else    v = ((const u16*)ps[slot])[off];
      VEC[idx] = v;
    }
  } else {                    // edge mask tiles
    int r = bi - 4097;
    int qt32 = r & 31, nt = (r >> 5) & 31, b = r >> 10;
    int f = t >> 6, l = t & 63;
    int nl = l & 31, h = l >> 5;
    int key  = ((f >> 1) << 5) + nl;
    int qrow = ((f & 1) << 4) + h * 8;
    const int* src = inc + ((size_t)(b * 2048 + nt * 64 + key)) * 1024 + qt32 * 32 + qrow;
    uint4 a = *(const uint4*)src;
    uint4 c = *(const uint4*)(src + 4);
    uint4 o;
    o.x = (a.x ? 0u : 0xC480u) | (a.y ? 0u : 0xC4800000u);
    o.y = (a.z ? 0u : 0xC480u) | (a.w ? 0u : 0xC4800000u);
    o.z = (c.x ? 0u : 0xC480u) | (c.y ? 0u : 0xC4800000u);
    o.w = (c.z ? 0u : 0xC480u) | (c.w ? 0u : 0xC4800000u);
    u16* dst = (b < 2 ? T0 + (size_t)b * 2097152 : T1 + (size_t)(b - 2) * 2097152)
               + ((size_t)nt * 32 + qt32) * 2048 + t * 8;
    *(uint4*)dst = o;
  }
}

// ---------------------------------------------------------------------------
// V transpose v3 (unchanged)
// ---------------------------------------------------------------------------
__global__ __launch_bounds__(256) void transposeV(const u16* __restrict__ Vp,
                                                  u16* __restrict__ VT, int Lk) {
  __shared__ u16 tile[64][72];
  int t = threadIdx.x;
  int nt = blockIdx.x;
  int bh = blockIdx.y;
  int nw = Lk >> 6;
  const u16* src = Vp + ((size_t)bh * Lk + nt * 64) * 64;
  int key = t >> 2, seg = t & 3;
  int dc0 = seg * 2, dc1 = seg * 2 + 1;
  uint4 a  = *(const uint4*)(src + key * 64 + ((dc0 ^ (key & 7)) << 3));
  uint4 b2 = *(const uint4*)(src + key * 64 + ((dc1 ^ (key & 7)) << 3));
  *(uint4*)&tile[key][dc0 * 8] = a;
  *(uint4*)&tile[key][dc1 * 8] = b2;
  __syncthreads();
  int d = t >> 2;
  u32 wb[8];
  #pragma unroll
  for (int i = 0; i < 8; ++i) {
    u32 lo = tile[seg * 16 + 2 * i][d];
    u32 hi = tile[seg * 16 + 2 * i + 1][d];
    wb[i] = lo | (hi << 16);
  }
  u16* base = VT + (((size_t)bh * nw + nt) * 64 + d) * 64;
  int kc0 = seg * 2, kc1 = seg * 2 + 1;
  uint4 o0; o0.x = wb[0]; o0.y = wb[1]; o0.z = wb[2]; o0.w = wb[3];
  uint4 o1; o1.x = wb[4]; o1.y = wb[5]; o1.z = wb[6]; o1.w = wb[7];
  *(uint4*)(base + ((kc0 ^ (d & 7)) << 3)) = o0;
  *(uint4*)(base + ((kc1 ^ (d & 7)) << 3)) = o1;
}

// NODE mask tiles (unchanged): key=m (Lk=1024), qrow=n (Lq=2048)
__global__ __launch_bounds__(256) void inc_tiles_node(const int* __restrict__ inc,
                                                      u16* __restrict__ T0,
                                                      u16* __restrict__ T1) {
  int qt32 = blockIdx.x, nt = blockIdx.y, b = blockIdx.z;
  int t = threadIdx.x;
  int f = t >> 6, l = t & 63;
  int nl = l & 31, h = l >> 5;
  int key  = ((f >> 1) << 5) + nl;
  int qrow = ((f & 1) << 4) + h * 8;
  const int* src = inc + ((size_t)(b * 2048 + qt32 * 32 + qrow)) * 1024 + nt * 64 + key;
  u16 o[8];
  #pragma unroll
  for (int e = 0; e < 8; ++e)
    o[e] = src[(size_t)e * 1024] ? (u16)0 : (u16)0xC480;
  uint4 ov;
  ov.x = (u32)o[0] | ((u32)o[1] << 16);
  ov.y = (u32)o[2] | ((u32)o[3] << 16);
  ov.z = (u32)o[4] | ((u32)o[5] << 16);
  ov.w = (u32)o[6] | ((u32)o[7] << 16);
  u16* dst = (b < 3 ? T0 + (size_t)b * 2097152 : T1)
             + ((size_t)nt * 64 + qt32) * 2048 + t * 8;
  *(uint4*)dst = ov;
}

// ---------------------------------------------------------------------------
// GEMM v5 (round 10): r9's fragment-ordered direct-B + T14 DISTANCE —
// B(kk+1) fragments prefetched into REGISTERS at the top of iter kk (one
// full K-iteration of latency cover, ~2000cyc >> L2 ~250cyc).  r9's miss:
// B loads sat in-iteration with only MFMA-issue distance.  kk loop fully
// unrolled so all array indices are compile-time (no scratch).  LDS 32KB
// (A only); launch_bounds(256,3) -> 3 blocks/CU (VGPR ~170).
// A3 path: blocksPerMat=256, grid 896 -> blocks 768..895 are mat=3 (QE).
// ---------------------------------------------------------------------------
__global__ __launch_bounds__(256, 3) void gemm_tiled(const u16* __restrict__ A,
                                                  const u16* __restrict__ FWt0, u32 wtStride,
                                                  const u16* __restrict__ bias0, u32 bStride,
                                                  u16* __restrict__ C0, u32 cStride,
                                                  int act, int blocksPerMat,
                                                  u32 modeMask, int lkshift,
                                                  void* __restrict__ out2, size_t out2_off,
                                                  const u16* __restrict__ A3,
                                                  const u32* __restrict__ flag) {
  __shared__ u16 As[2][8192];   // [row:128][slot:8][8], slot = chunk^(row&7)
  int mat = blockIdx.x / blocksPerMat;
  int blk = blockIdx.x % blocksPerMat;
  const u16* Fw = FWt0 + (size_t)mat * wtStride;
  const u16* bias = bias0 + (size_t)mat * bStride;
  u16* C = C0 + (size_t)mat * cStride;
  int mode = (modeMask >> mat) & 1u;
  int f32o = out2 ? (int)(*flag) : 0;
  const u16* Am = (A3 && mat == 3) ? A3 : A;
  int tm = blk >> 2, tn = blk & 3;
  int m0 = tm * 128, n0 = tn * 128;

  int t = threadIdx.x;
  int wave = t >> 6, lane = t & 63;
  int nl = lane & 31, h32 = lane >> 5;
  int wm = wave >> 1, wn = wave & 1;

  int srow = lane >> 3;
  int gch  = (lane & 7) ^ srow;
  const u16* Ab = Am + ((size_t)m0 + wave * 32) * 512 + (size_t)srow * 512 + gch * 8;
  u16* AsW = &As[0][0] + wave * 32 * 64;

  // fragment-ordered B bases: slab(n32,kk,ks) = ((n32*8+kk)*4+ks)*512
  int n32_0 = tn * 4 + wn * 2;
  const u16* Bf0 = Fw + (size_t)n32_0 * 16384 + lane * 8;
  const u16* Bf1 = Bf0 + 16384;

  #pragma unroll
  for (int c = 0; c < 4; ++c)
    dma16(Ab + (size_t)c * 8 * 512, AsW + c * 8 * 64);
  // prologue: B fragments for kk=0
  bf16x8 b0c[4], b1c[4];
  #pragma unroll
  for (int ks = 0; ks < 4; ++ks) {
    b0c[ks] = *(const bf16x8*)(Bf0 + ks * 512);
    b1c[ks] = *(const bf16x8*)(Bf1 + ks * 512);
  }
  __syncthreads();

  f32x16 a00 = {}, a01 = {}, a10 = {}, a11 = {};

  #pragma unroll
  for (int kk = 0; kk < 8; ++kk) {
    int buf = kk & 1;
    bf16x8 b0n[4], b1n[4];
    if (kk + 1 < 8) {
      int k0n = (kk + 1) * 64;
      u16* AD = &As[buf ^ 1][0] + wave * 32 * 64;
      #pragma unroll
      for (int c = 0; c < 4; ++c)
        dma16(Ab + (size_t)c * 8 * 512 + k0n, AD + c * 8 * 64);
      #pragma unroll
      for (int ks = 0; ks < 4; ++ks) {
        b0n[ks] = *(const bf16x8*)(Bf0 + ((kk + 1) * 4 + ks) * 512);
        b1n[ks] = *(const bf16x8*)(Bf1 + ((kk + 1) * 4 + ks) * 512);
      }
    }
    const u16* Ab_s = &As[buf][0];
    int ar0 = wm * 64 + nl, ar1 = wm * 64 + 32 + nl;
    #pragma unroll
    for (int ks = 0; ks < 4; ++ks) {
      int ch = ks * 2 + h32;
      int sw = ((ch ^ (nl & 7)) << 3);
      bf16x8 fa0 = *(const bf16x8*)(Ab_s + ar0 * 64 + sw);
      bf16x8 fa1 = *(const bf16x8*)(Ab_s + ar1 * 64 + sw);
      a00 = __builtin_amdgcn_mfma_f32_32x32x16_bf16(fa0, b0c[ks], a00, 0, 0, 0);
      a01 = __builtin_amdgcn_mfma_f32_32x32x16_bf16(fa0, b1c[ks], a01, 0, 0, 0);
      a10 = __builtin_amdgcn_mfma_f32_32x32x16_bf16(fa1, b0c[ks], a10, 0, 0, 0);
      a11 = __builtin_amdgcn_mfma_f32_32x32x16_bf16(fa1, b1c[ks], a11, 0, 0, 0);
    }
    if (kk + 1 < 8) {
      #pragma unroll
      for (int ks = 0; ks < 4; ++ks) { b0c[ks] = b0n[ks]; b1c[ks] = b1n[ks]; }
    }
    __syncthreads();
  }

  int nw = 1 << (lkshift - 6);
  #pragma unroll
  for (int am = 0; am < 2; ++am) {
    #pragma unroll
    for (int bn = 0; bn < 2; ++bn) {
      const f32x16* accp = am == 0 ? (bn == 0 ? &a00 : &a01)
                                   : (bn == 0 ? &a10 : &a11);
      f32x16 acc = *accp;
      int cn = n0 + wn * 64 + bn * 32 + nl;
      float bv = bf2f(bias[cn]);
      #pragma unroll
      for (int g = 0; g < 16; ++g) {
        int rm = m0 + wm * 64 + am * 32 + (g & 3) + 8 * (g >> 2) + 4 * h32;
        float v = acc[g] + bv;
        if (act) v = gelu_f(v);
        if (mode) {
          int bb = rm >> lkshift;
          int key = rm & ((1 << lkshift) - 1);
          int nt = key >> 6, kl = key & 63;
          int d = cn & 63;
          size_t ad = ((((size_t)bb * 8 + (cn >> 6)) * nw + nt) * 64 + kl) * 64
                      + (((d >> 3) ^ (kl & 7)) << 3) + (d & 7);
          C[ad] = f2bf(v);
        } else {
          size_t ad = (size_t)rm * 512 + cn;
          C[ad] = f2bf(v);
          if (out2) {
            if (f32o) ((float*)out2)[out2_off + ad] = v;
            else      ((u16*)out2)[out2_off + ad] = f2bf(v);
          }
        }
      }
    }
  }
}

// ---------------------------------------------------------------------------
// MFMA flash v13 (UNCHANGED): 4-wave shared K/V staging, mask-MFMA,
// triple-buffered DMA with counted vmcnt(8) across raw s_barrier.
// ---------------------------------------------------------------------------
__global__ __launch_bounds__(256, 4) void flash_mfma(
    const u16* __restrict__ Q,      // [B*Lq][512] row-major
    const u16* __restrict__ Kp,     // [bh:32][nt][kl:64][d-swizzled:64]
    const u16* __restrict__ VTp,    // [bh][nt][d:64][key-swizzled:64]
    const u16* __restrict__ IncA,   // mask tiles, batches < nbA
    const u16* __restrict__ IncB,   // mask tiles, batches >= nbA
    int nbA,
    void* __restrict__ Outv,
    u16* __restrict__ Opart, float* __restrict__ Lpart,
    int Lq, int Lk, int splits, int is_final, const u32* __restrict__ flag) {
  __shared__ u16 K_s[3][4096];
  __shared__ u16 V_s[3][4096];
  __shared__ u16 P_s[4][2048];

  int t = threadIdx.x;
  int wave = t >> 6, lane = t & 63;
  int nl = lane & 31, h32 = lane >> 5;
  int qtiles = Lq >> 7;              // 128-row q-tiles (4 waves x 32)
  int nwords = Lk >> 6;
  int chunk = (int)(gridDim.x >> 3);
  int wid = (blockIdx.x & 7) * chunk + (blockIdx.x >> 3);
  int r2 = wid % (qtiles * 32);
  int split = wid / (qtiles * 32);
  int qt = r2 % qtiles;
  int bh = r2 / qtiles;
  int h = bh & 7, b = bh >> 3;
  int row0 = qt * 128 + wave * 32;
  int per = nwords / splits;
  int tile0 = split * per;
  int f32o = is_final ? (int)(*flag) : 0;

  bf16x8 qf[4];
  {
    const u16* qp = Q + ((size_t)(b * Lq) + row0 + nl) * 512 + h * 64 + h32 * 8;
    #pragma unroll
    for (int ks = 0; ks < 4; ++ks) qf[ks] = *(const bf16x8*)(qp + ks * 16);
  }
  bf16x8 b0f = {}, b16f = {};
  #pragma unroll
  for (int e = 0; e < 8; ++e) {
    b0f[e]  = (nl == h32 * 8 + e)      ? (short)0x3F80 : (short)0;
    b16f[e] = (nl == 16 + h32 * 8 + e) ? (short)0x3F80 : (short)0;
  }

  const u16* Kbh = Kp + (size_t)bh * Lk * 64;
  const u16* Vbh = VTp + (size_t)bh * nwords * 4096;
  size_t tstr = (size_t)(Lq >> 5) * 2048;
  int qt2 = row0 >> 5;
  const u16* It = (b < nbA ? IncA + (size_t)b * 2097152
                           : IncB + (size_t)(b - nbA) * 2097152)
                  + (size_t)qt2 * 2048 + lane * 8;

  f32x16 o0 = {}, o1 = {};
  float lsum = 0.f;

  {
    const u16* TK = Kbh + (size_t)tile0 * 4096;
    const u16* TV = Vbh + (size_t)tile0 * 4096;
    #pragma unroll
    for (int c = 0; c < 2; ++c) {
      int ch = c * 4 + wave;
      dma16(TK + ch * 512 + lane * 8, &K_s[0][ch * 512]);
      dma16(TV + ch * 512 + lane * 8, &V_s[0][ch * 512]);
    }
    asm volatile("" ::: "memory");
    if (per > 1) {
      const u16* TK1 = TK + 4096;
      const u16* TV1 = TV + 4096;
      #pragma unroll
      for (int c = 0; c < 2; ++c) {
        int ch = c * 4 + wave;
        dma16(TK1 + ch * 512 + lane * 8, &K_s[1][ch * 512]);
        dma16(TV1 + ch * 512 + lane * 8, &V_s[1][ch * 512]);
      }
    }
    asm volatile("" ::: "memory");
  }
  bf16x8 mc0, mc1, mc2, mc3;
  {
    const u16* p = It + (size_t)tile0 * tstr;
    mc0 = *(const bf16x8*)(p);
    mc1 = *(const bf16x8*)(p + 512);
    mc2 = *(const bf16x8*)(p + 1024);
    mc3 = *(const bf16x8*)(p + 1536);
  }
  __syncthreads();

  for (int i = 0; i < per; ++i) {
    int nt = tile0 + i;
    int bi = i % 3;
    bf16x8 mn0, mn1, mn2, mn3;
    if (i + 2 < per) {
      int bd = (i + 2) % 3;
      const u16* TK = Kbh + (size_t)(nt + 2) * 4096;
      const u16* TV = Vbh + (size_t)(nt + 2) * 4096;
      #pragma unroll
      for (int c = 0; c < 2; ++c) {
        int ch = c * 4 + wave;
        dma16(TK + ch * 512 + lane * 8, &K_s[bd][ch * 512]);
        dma16(TV + ch * 512 + lane * 8, &V_s[bd][ch * 512]);
      }
    }
    asm volatile("" ::: "memory");
    if (i + 1 < per) {
      const u16* p = It + (size_t)(nt + 1) * tstr;
      mn0 = *(const bf16x8*)(p);
      mn1 = *(const bf16x8*)(p + 512);
      mn2 = *(const bf16x8*)(p + 1024);
      mn3 = *(const bf16x8*)(p + 1536);
    }

    f32x16 s0 = {}, s1 = {};
    #pragma unroll
    for (int ks = 0; ks < 4; ++ks) {
      int ch = ks * 2 + h32;
      bf16x8 k0 = *(const bf16x8*)&K_s[bi][nl * 64 + ((ch ^ (nl & 7)) << 3)];
      bf16x8 k1 = *(const bf16x8*)&K_s[bi][(32 + nl) * 64 + ((ch ^ (nl & 7)) << 3)];
      s0 = __builtin_amdgcn_mfma_f32_32x32x16_bf16(k0, qf[ks], s0, 0, 0, 0);
      s1 = __builtin_amdgcn_mfma_f32_32x32x16_bf16(k1, qf[ks], s1, 0, 0, 0);
    }
    s0 = __builtin_amdgcn_mfma_f32_32x32x16_bf16(mc0, b0f,  s0, 0, 0, 0);
    s0 = __builtin_amdgcn_mfma_f32_32x32x16_bf16(mc1, b16f, s0, 0, 0, 0);
    s1 = __builtin_amdgcn_mfma_f32_32x32x16_bf16(mc2, b0f,  s1, 0, 0, 0);
    s1 = __builtin_amdgcn_mfma_f32_32x32x16_bf16(mc3, b16f, s1, 0, 0, 0);

    #pragma unroll
    for (int gg = 0; gg < 4; ++gg) {
      float pv0[4], pv1[4];
      #pragma unroll
      for (int r = 0; r < 4; ++r) {
        int g = gg * 4 + r;
        float e0 = exp2f(fmaf(s0[g], SC2, -CS2));
        float e1 = exp2f(fmaf(s1[g], SC2, -CS2));
        pv0[r] = e0;
        pv1[r] = e1;
        lsum += e0 + e1;
      }
      uint2 a0, a1;
      a0.x = cvtpk(pv0[0], pv0[1]);
      a0.y = cvtpk(pv0[2], pv0[3]);
      a1.x = cvtpk(pv1[0], pv1[1]);
      a1.y = cvtpk(pv1[2], pv1[3]);
      *(uint2*)&P_s[wave][gg * 256 + nl * 8 + 4 * h32]       = a0;
      *(uint2*)&P_s[wave][(4 + gg) * 256 + nl * 8 + 4 * h32] = a1;
    }
    asm volatile("s_waitcnt lgkmcnt(0)" ::: "memory");
    #pragma unroll
    for (int ks2 = 0; ks2 < 4; ++ks2) {
      int ch = ks2 * 2 + h32;
      bf16x8 pf = *(const bf16x8*)&P_s[wave][ch * 256 + nl * 8];
      bf16x8 v0 = *(const bf16x8*)&V_s[bi][nl * 64 + ((ch ^ (nl & 7)) << 3)];
      bf16x8 v1 = *(const bf16x8*)&V_s[bi][(32 + nl) * 64 + ((ch ^ (nl & 7)) << 3)];
      o0 = __builtin_amdgcn_mfma_f32_32x32x16_bf16(pf, v0, o0, 0, 0, 0);
      o1 = __builtin_amdgcn_mfma_f32_32x32x16_bf16(pf, v1, o1, 0, 0, 0);
    }
    mc0 = mn0; mc1 = mn1; mc2 = mn2; mc3 = mn3;
    asm volatile("s_waitcnt vmcnt(8)" ::: "memory");
    __builtin_amdgcn_s_barrier();
  }
  lsum += __shfl_xor(lsum, 32);

  if (Opart) {
    u16* ob = Opart + (size_t)split * 2097152;
    #pragma unroll
    for (int g = 0; g < 16; ++g) {
      int m = (g & 3) + 8 * (g >> 2) + 4 * h32;
      size_t base = ((size_t)(b * Lq) + row0 + m) * 512 + h * 64;
      ob[base + nl]      = f2bf(o0[g]);
      ob[base + 32 + nl] = f2bf(o1[g]);
    }
    if (h32 == 0)
      Lpart[(size_t)split * 32768 + ((size_t)(b * Lq) + row0 + nl) * 8 + h] = lsum;
  } else {
    #pragma unroll
    for (int g = 0; g < 16; ++g) {
      int m = (g & 3) + 8 * (g >> 2) + 4 * h32;
      float lv = __shfl(lsum, m);
      float inv = 1.0f / (lv + 1e-30f);
      size_t base = ((size_t)(b * Lq) + row0 + m) * 512 + h * 64;
      float v0 = gelu_f(o0[g] * inv);
      float v1 = gelu_f(o1[g] * inv);
      if (f32o) {
        ((float*)Outv)[base + nl]      = v0;
        ((float*)Outv)[base + 32 + nl] = v1;
      } else {
        ((u16*)Outv)[base + nl]      = f2bf(v0);
        ((u16*)Outv)[base + 32 + nl] = f2bf(v1);
      }
    }
  }
}

// ---------------------------------------------------------------------------
// Fused: combine edge split-K partials + residual + LayerNorm (eps=1e-7)
// ---------------------------------------------------------------------------
__global__ __launch_bounds__(256) void ln_fused(const u16* __restrict__ Op,
                                                const float* __restrict__ Lp,
                                                const u16* __restrict__ E,
                                                const u16* __restrict__ g,
                                                const u16* __restrict__ bb,
                                                u16* __restrict__ out) {
  int r = blockIdx.x;
  int t = threadIdx.x;
  int e = t * 2;
  int h = e >> 6;
  float lv = Lp[r * 8 + h] + Lp[32768 + r * 8 + h] + 1e-30f;
  float inv = 1.0f / lv;
  size_t idx = (size_t)r * 512 + e;
  u32 u0 = *(const u32*)&Op[idx];
  u32 u1 = *(const u32*)&Op[2097152 + idx];
  u32 ue = *(const u32*)&E[idx];
  float x0 = bf2f((u16)(ue & 0xffffu)) +
             gelu_f((bf2f((u16)(u0 & 0xffffu)) + bf2f((u16)(u1 & 0xffffu))) * inv);
  float x1 = bf2f((u16)(ue >> 16)) +
             gelu_f((bf2f((u16)(u0 >> 16)) + bf2f((u16)(u1 >> 16))) * inv);
  float s = x0 + x1, q = x0 * x0 + x1 * x1;
  #pragma unroll
  for (int o = 32; o; o >>= 1) { s += __shfl_down(s, o); q += __shfl_down(q, o); }
  __shared__ float red[8];
  int wv = t >> 6, ln = t & 63;
  if (ln == 0) { red[wv] = s; red[4 + wv] = q; }
  __syncthreads();
  s = red[0] + red[1] + red[2] + red[3];
  q = red[4] + red[5] + red[6] + red[7];
  float mean = s * (1.f / 512.f);
  float var  = q * (1.f / 512.f) - mean * mean;
  float rs = rsqrtf(var + 1e-7f);
  u32 ug = *(const u32*)(g + e);
  u32 ub = *(const u32*)(bb + e);
  float y0 = (x0 - mean) * rs * bf2f((u16)(ug & 0xffffu)) + bf2f((u16)(ub & 0xffffu));
  float y1 = (x1 - mean) * rs * bf2f((u16)(ug >> 16)) + bf2f((u16)(ub >> 16));
  *(u32*)(out + idx) = (u32)f2bf(y0) | ((u32)f2bf(y1) << 16);
}

// ---------------------------------------------------------------------------
extern "C" void kernel_launch(void* const* d_in, const int* in_sizes, int n_in,
                              void* d_out, int out_size, void* d_ws, size_t ws_size,
                              hipStream_t stream) {
  (void)in_sizes; (void)n_in; (void)out_size;
  const int* inc = (const int*)d_in[1];

  char* ws = (char*)d_ws;
  u32* FLAG = (u32*)ws;
  u16* VEC  = (u16*)(ws + 1024);
  u16* WT   = (u16*)(ws + 65536);     // 4MB FWT; gap 4259840..8454144 free
  u16* XB   = (u16*)(ws + 8454144);   // X bf16; later Opart; later node tiles b0-2
  u16* EB   = (u16*)(ws + 16842752);  // E bf16; later node tiles (b0-2 tail)
  u16* QN   = (u16*)(ws + 21037056);  // row-major [8192][512]; KN/VN/QE contiguous
  u16* KN   = (u16*)(ws + 29425664);  // K' node; later ELN+H1
  u16* VN   = (u16*)(ws + 37814272);  // V' node; later KE/VE
  u16* QE   = (u16*)(ws + 46202880);  // later node tiles b3
  u16* EATT = (u16*)(ws + 50397184);  // edge tiles b0,b1 (w/ EFIN slot); later VTe
  u16* EFIN = (u16*)(ws + 54591488);
  const size_t NEEDED = 60882944;
  u16* ELN = (u16*)(ws + 29425664);
  u16* H1  = (u16*)(ws + 33619968);
  u16* KE  = (u16*)(ws + 37814272);
  u16* Opart = XB;                        // 2 x 4MB bf16 edge partials
  float* Lpart = (float*)(ws + 4259840);  // 256KB in WT gap
  u16* ETIL0 = EATT;                      // edge mask tiles b0,b1 (8MB)
  u16* ETIL1 = (u16*)d_out + 4194304;     // edge mask tiles b2,b3 (d_out+8MB;
                                          //  dead until EFIN/node-flash writes)
  u16* NTIL0 = XB;                        // node mask tiles b0-2 (12MB XB+EB)
  u16* NTIL1 = QE;                        // node mask tiles b3 (4MB)
  u16* VTn = (u16*)d_out;                 // 8MB
  u16* VTe = EATT;
  u16* VE  = (u16*)(ws + 42008576);

  detect_dtype<<<1, 64, 0, stream>>>((const u16*)d_in[0], FLAG);

  if (ws_size < NEEDED) {
    fill_diag<<<8192, 256, 0, stream>>>((u32*)d_out,
                                        1000.0f + (float)(ws_size >> 20), FLAG);
    return;
  }

  // ALL independent prep in one launch: convX | convE | FWT build | vec10 |
  // edge mask tiles
  prep_all<<<8193, 256, 0, stream>>>(
      d_in[0], d_in[3], inc,
      d_in[4], d_in[6], d_in[8], d_in[10], d_in[12], d_in[14], d_in[16], d_in[18],
      d_in[5], d_in[7], d_in[9], d_in[11], d_in[13], d_in[15], d_in[17], d_in[19],
      d_in[20], d_in[21],
      XB, EB, WT, VEC, ETIL0, ETIL1, FLAG);

  // X projections Q/K/V + E projection Q_e in ONE launch (mats 0..3):
  // blocks 768..895 -> mat 3 (A3=EB), C lands at QN+3*cStride == QE.
  gemm_tiled<<<896, 256, 0, stream>>>(XB, WT, 262144, VEC, 512,
                                      QN, 4194304, 0, 256, 0b0110u, 11,
                                      nullptr, 0, EB, FLAG);

  // V_n -> tile-blocked swizzled VT'
  transposeV<<<dim3(32, 32), 256, 0, stream>>>(VN, VTn, 2048);

  // edge attends nodes: split-K=2 partials
  flash_mfma<<<512, 256, 0, stream>>>(QE, KN, VTn, ETIL0, ETIL1, 2, nullptr,
                                      Opart, Lpart, 1024, 2048, 2, 0, FLAG);

  // fused combine + residual + LN -> ELN  (frees XB/EB/QE)
  ln_fused<<<4096, 256, 0, stream>>>(Opart, Lpart, EB,
                                     VEC + 8 * 512, VEC + 9 * 512, ELN);

  // node mask tiles (b0-2 -> XB+EB; b3 -> QE slot)
  inc_tiles_node<<<dim3(64, 16, 4), 256, 0, stream>>>(inc, NTIL0, NTIL1);

  gemm_tiled<<<128, 256, 0, stream>>>(ELN, WT + 6 * 262144, 0, VEC + 6 * 512, 0,
                                      H1, 0, 1, 128, 0, 11, nullptr, 0,
                                      nullptr, FLAG);
  // EFIN GEMM also writes E_ output (d_out chunk 2) dtype-aware
  gemm_tiled<<<128, 256, 0, stream>>>(H1, WT + 7 * 262144, 0, VEC + 7 * 512, 0,
                                      EFIN, 0, 0, 128, 0, 11,
                                      d_out, 4194304, nullptr, FLAG);

  // edge K/V from E_final (batched, both mode1, lkshift=10; KE/VE contiguous)
  gemm_tiled<<<256, 256, 0, stream>>>(EFIN, WT + 4 * 262144, 262144, VEC + 4 * 512, 512,
                                      KE, 2097152, 0, 128, 0b11u, 10,
                                      nullptr, 0, nullptr, FLAG);
  transposeV<<<dim3(16, 32), 256, 0, stream>>>(VE, VTe, 1024);

  // node attends edges -> X_ (final, dtype-aware)
  flash_mfma<<<512, 256, 0, stream>>>(QN, KE, VTe, NTIL0, NTIL1, 3, d_out,
                                      nullptr, nullptr, 2048, 1024, 1, 1, FLAG);
}

// Round 11
// 349.849 us; speedup vs baseline: 1.0424x; 1.0424x over previous
//
#include <hip/hip_runtime.h>

typedef unsigned short u16;
typedef unsigned int   u32;
typedef unsigned long long u64;

typedef __attribute__((ext_vector_type(8))) short  bf16x8;
typedef __attribute__((ext_vector_type(16))) float f32x16;

#define SC2 0.1803368801111243f    // SCALE(0.125) * log2(e)
#define CS2 11.541560327111707f    // 8 * log2(e)  (fixed softmax shift)

__device__ __forceinline__ float bf2f(u16 h) { return __uint_as_float(((u32)h) << 16); }
__device__ __forceinline__ u16 f2bf(float f) {
  u32 u = __float_as_uint(f);
  return (u16)((u + 0x7FFFu + ((u >> 16) & 1u)) >> 16);   // RNE
}
__device__ __forceinline__ float gelu_f(float x) {
  return 0.5f * x * (1.0f + erff(x * 0.70710678118654752440f));
}
// async global->LDS DMA, 16B/lane (lane i -> ldsbase + i*16)
__device__ __forceinline__ void dma16(const u16* g, u16* l) {
  __builtin_amdgcn_global_load_lds(
      (const __attribute__((address_space(1))) u32*)g,
      (__attribute__((address_space(3))) u32*)l, 16, 0, 0);
}
// 2xf32 -> packed bf16 (RNE), 1 VALU op (no builtin on gfx950)
__device__ __forceinline__ u32 cvtpk(float lo, float hi) {
  u32 r;
  asm("v_cvt_pk_bf16_f32 %0, %1, %2" : "=v"(r) : "v"(lo), "v"(hi));
  return r;
}

// ---------------------------------------------------------------------------
// dtype detection (flag=1 -> fp32 inputs; HW-confirmed fp32)
// ---------------------------------------------------------------------------
__global__ void detect_dtype(const u16* __restrict__ X, u32* __restrict__ flag) {
  int lane = threadIdx.x;
  int bad = 0;
  #pragma unroll
  for (int i = 0; i < 8; ++i) {
    u16 v = X[i * 64 + lane];
    int e = (v >> 7) & 0xFF;
    if (e >= 0x88) bad++;
  }
  #pragma unroll
  for (int o = 1; o < 64; o <<= 1) bad += __shfl_xor(bad, o);
  if (lane == 0) *flag = (bad > 16) ? 1u : 0u;
}

__global__ __launch_bounds__(256) void fill_diag(u32* __restrict__ out, float base,
                                                 const u32* __restrict__ flag) {
  float v = base + (*flag ? 4000.0f : 0.0f);
  u16 h = f2bf(v);
  out[blockIdx.x * 256 + threadIdx.x] = (u32)h | ((u32)h << 16);
}

// ---------------------------------------------------------------------------
// Fused prep (round-7 proven): convX | convE | wtrans | vec10 |
// inc_tiles_edge in ONE launch.
//   blocks [0,2048)      : X fp32/bf16 -> XB bf16
//   blocks [2048,3072)   : E -> EB
//   blocks [3072,5120)   : 8 weights convert+transpose -> WT (row-major W^T)
//   block  5120          : 10 bias vecs -> VEC
//   blocks [5121,9217)   : edge mask tiles -> ETIL0 (b0,b1) / ETIL1 (b2,b3)
// ---------------------------------------------------------------------------
__global__ __launch_bounds__(256) void prep_all(
    const void* __restrict__ Xsrc, const void* __restrict__ Esrc,
    const int* __restrict__ inc,
    const void* w0, const void* w1, const void* w2, const void* w3,
    const void* w4, const void* w5, const void* w6, const void* w7,
    const void* p0, const void* p1, const void* p2, const void* p3, const void* p4,
    const void* p5, const void* p6, const void* p7, const void* p8, const void* p9,
    u16* __restrict__ XB, u16* __restrict__ EB, u16* __restrict__ WT,
    u16* __restrict__ VEC, u16* __restrict__ T0, u16* __restrict__ T1,
    const u32* __restrict__ flag) {
  int bi = blockIdx.x;
  int t = threadIdx.x;
  int fl = (int)(*flag);

  if (bi < 3072) {            // conv X (bi<2048) / conv E
    const void* src = bi < 2048 ? Xsrc : Esrc;
    u16* dst = bi < 2048 ? XB : EB;
    int base = bi < 2048 ? bi : bi - 2048;
    int i = (base * 256 + t) * 8;
    if (fl) {
      const float* s = (const float*)src + i;
      float4 a = *(const float4*)s;
      float4 b = *(const float4*)(s + 4);
      uint4 o;
      o.x = (u32)f2bf(a.x) | ((u32)f2bf(a.y) << 16);
      o.y = (u32)f2bf(a.z) | ((u32)f2bf(a.w) << 16);
      o.z = (u32)f2bf(b.x) | ((u32)f2bf(b.y) << 16);
      o.w = (u32)f2bf(b.z) | ((u32)f2bf(b.w) << 16);
      *(uint4*)(dst + i) = o;
    } else {
      *(uint4*)(dst + i) = *(const uint4*)((const u16*)src + i);
    }
  } else if (bi < 5120) {     // weight transpose
    const void* wsrc[8] = {w0, w1, w2, w3, w4, w5, w6, w7};
    __shared__ u16 tile[32][33];
    int r = bi - 3072;
    int bx = (r & 15) * 32, by = ((r >> 4) & 15) * 32, z = r >> 8;
    const void* W = wsrc[z];
    u16* Wt = WT + (size_t)z * 262144;
    int tx = t & 31, ty = t >> 5;
    #pragma unroll
    for (int i = 0; i < 4; ++i) {
      int rr = ty + 8 * i;
      size_t src = (size_t)(by + rr) * 512 + bx + tx;
      tile[rr][tx] = fl ? f2bf(((const float*)W)[src]) : ((const u16*)W)[src];
    }
    __syncthreads();
    #pragma unroll
    for (int i = 0; i < 4; ++i) {
      int rr = ty + 8 * i;
      Wt[(size_t)(bx + rr) * 512 + by + tx] = tile[tx][rr];
    }
  } else if (bi == 5120) {    // bias vectors
    const void* ps[10] = {p0, p1, p2, p3, p4, p5, p6, p7, p8, p9};
    for (int idx = t; idx < 5120; idx += 256) {
      int slot = idx >> 9, off = idx & 511;
      u16 v;
      if (fl) v = f2bf(((const float*)ps[slot])[off]);
      else    v = ((const u16*)ps[slot])[off];
      VEC[idx] = v;
    }
  } else {                    // edge mask tiles
    int r = bi - 5121;
    int qt32 = r & 31, nt = (r >> 5) & 31, b = r >> 10;
    int f = t >> 6, l = t & 63;
    int nl = l & 31, h = l >> 5;
    int key  = ((f >> 1) << 5) + nl;
    int qrow = ((f & 1) << 4) + h * 8;
    const int* src = inc + ((size_t)(b * 2048 + nt * 64 + key)) * 1024 + qt32 * 32 + qrow;
    uint4 a = *(const uint4*)src;
    uint4 c = *(const uint4*)(src + 4);
    uint4 o;
    o.x = (a.x ? 0u : 0xC480u) | (a.y ? 0u : 0xC4800000u);
    o.y = (a.z ? 0u : 0xC480u) | (a.w ? 0u : 0xC4800000u);
    o.z = (c.x ? 0u : 0xC480u) | (c.y ? 0u : 0xC4800000u);
    o.w = (c.z ? 0u : 0xC480u) | (c.w ? 0u : 0xC4800000u);
    u16* dst = (b < 2 ? T0 + (size_t)b * 2097152 : T1 + (size_t)(b - 2) * 2097152)
               + ((size_t)nt * 32 + qt32) * 2048 + t * 8;
    *(uint4*)dst = o;
  }
}

// ---------------------------------------------------------------------------
// V transpose v3 (unchanged)
// ---------------------------------------------------------------------------
__global__ __launch_bounds__(256) void transposeV(const u16* __restrict__ Vp,
                                                  u16* __restrict__ VT, int Lk) {
  __shared__ u16 tile[64][72];
  int t = threadIdx.x;
  int nt = blockIdx.x;
  int bh = blockIdx.y;
  int nw = Lk >> 6;
  const u16* src = Vp + ((size_t)bh * Lk + nt * 64) * 64;
  int key = t >> 2, seg = t & 3;
  int dc0 = seg * 2, dc1 = seg * 2 + 1;
  uint4 a  = *(const uint4*)(src + key * 64 + ((dc0 ^ (key & 7)) << 3));
  uint4 b2 = *(const uint4*)(src + key * 64 + ((dc1 ^ (key & 7)) << 3));
  *(uint4*)&tile[key][dc0 * 8] = a;
  *(uint4*)&tile[key][dc1 * 8] = b2;
  __syncthreads();
  int d = t >> 2;
  u32 wb[8];
  #pragma unroll
  for (int i = 0; i < 8; ++i) {
    u32 lo = tile[seg * 16 + 2 * i][d];
    u32 hi = tile[seg * 16 + 2 * i + 1][d];
    wb[i] = lo | (hi << 16);
  }
  u16* base = VT + (((size_t)bh * nw + nt) * 64 + d) * 64;
  int kc0 = seg * 2, kc1 = seg * 2 + 1;
  uint4 o0; o0.x = wb[0]; o0.y = wb[1]; o0.z = wb[2]; o0.w = wb[3];
  uint4 o1; o1.x = wb[4]; o1.y = wb[5]; o1.z = wb[6]; o1.w = wb[7];
  *(uint4*)(base + ((kc0 ^ (d & 7)) << 3)) = o0;
  *(uint4*)(base + ((kc1 ^ (d & 7)) << 3)) = o1;
}

// NODE mask tiles (unchanged): key=m (Lk=1024), qrow=n (Lq=2048)
__global__ __launch_bounds__(256) void inc_tiles_node(const int* __restrict__ inc,
                                                      u16* __restrict__ T0,
                                                      u16* __restrict__ T1) {
  int qt32 = blockIdx.x, nt = blockIdx.y, b = blockIdx.z;
  int t = threadIdx.x;
  int f = t >> 6, l = t & 63;
  int nl = l & 31, h = l >> 5;
  int key  = ((f >> 1) << 5) + nl;
  int qrow = ((f & 1) << 4) + h * 8;
  const int* src = inc + ((size_t)(b * 2048 + qt32 * 32 + qrow)) * 1024 + nt * 64 + key;
  u16 o[8];
  #pragma unroll
  for (int e = 0; e < 8; ++e)
    o[e] = src[(size_t)e * 1024] ? (u16)0 : (u16)0xC480;
  uint4 ov;
  ov.x = (u32)o[0] | ((u32)o[1] << 16);
  ov.y = (u32)o[2] | ((u32)o[3] << 16);
  ov.z = (u32)o[4] | ((u32)o[5] << 16);
  ov.w = (u32)o[6] | ((u32)o[7] << 16);
  u16* dst = (b < 3 ? T0 + (size_t)b * 2097152 : T1)
             + ((size_t)nt * 64 + qt32) * 2048 + t * 8;
  *(uint4*)dst = ov;
}

// ---------------------------------------------------------------------------
// GEMM (round-7 proven: As+Bs LDS double-buffer, DMA-staged) + round-11
// XCD chunked swizzle (T1, bijective: all grids %8==0).  B-direct family
// (r8/r9/r10) refuted — compiler defeats register pipelines; LDS staging is
// the mechanism that gives B loads distance.  A3 path: blocksPerMat=256,
// grid 896 -> blocks 768..895 are mat=3 (QE projection, A3=EB).
// ---------------------------------------------------------------------------
__global__ __launch_bounds__(256) void gemm_tiled(const u16* __restrict__ A,
                                                  const u16* __restrict__ Wt0, u32 wtStride,
                                                  const u16* __restrict__ bias0, u32 bStride,
                                                  u16* __restrict__ C0, u32 cStride,
                                                  int act, int blocksPerMat,
                                                  u32 modeMask, int lkshift,
                                                  void* __restrict__ out2, size_t out2_off,
                                                  const u16* __restrict__ A3,
                                                  const u32* __restrict__ flag) {
  __shared__ u16 As[2][8192];   // [row:128][slot:8][8], slot = chunk^(row&7)
  __shared__ u16 Bs[2][8192];
  // XCD chunked swizzle: co-locate consecutive blocks (shared A/B panels)
  // on one XCD's L2 instead of round-robin 8x duplication.
  int wid = (blockIdx.x & 7) * (int)(gridDim.x >> 3) + (blockIdx.x >> 3);
  int mat = wid / blocksPerMat;
  int blk = wid % blocksPerMat;
  const u16* Wt = Wt0 + (size_t)mat * wtStride;
  const u16* bias = bias0 + (size_t)mat * bStride;
  u16* C = C0 + (size_t)mat * cStride;
  int mode = (modeMask >> mat) & 1u;
  int f32o = out2 ? (int)(*flag) : 0;
  const u16* Am = (A3 && mat == 3) ? A3 : A;
  int tm = blk >> 2, tn = blk & 3;
  int m0 = tm * 128, n0 = tn * 128;

  int t = threadIdx.x;
  int wave = t >> 6, lane = t & 63;
  int nl = lane & 31, h32 = lane >> 5;
  int wm = wave >> 1, wn = wave & 1;

  int srow = lane >> 3;
  int gch  = (lane & 7) ^ srow;
  const u16* Ab = Am + ((size_t)m0 + wave * 32) * 512 + (size_t)srow * 512 + gch * 8;
  const u16* Bb = Wt + ((size_t)n0 + wave * 32) * 512 + (size_t)srow * 512 + gch * 8;
  u16* AsW = &As[0][0] + wave * 32 * 64;
  u16* BsW = &Bs[0][0] + wave * 32 * 64;

  #pragma unroll
  for (int c = 0; c < 4; ++c) {
    dma16(Ab + (size_t)c * 8 * 512, AsW + c * 8 * 64);
    dma16(Bb + (size_t)c * 8 * 512, BsW + c * 8 * 64);
  }
  __syncthreads();

  f32x16 a00 = {}, a01 = {}, a10 = {}, a11 = {};

  for (int kk = 0; kk < 8; ++kk) {
    int buf = kk & 1;
    if (kk + 1 < 8) {
      int k0n = (kk + 1) * 64;
      u16* AD = &As[buf ^ 1][0] + wave * 32 * 64;
      u16* BD = &Bs[buf ^ 1][0] + wave * 32 * 64;
      #pragma unroll
      for (int c = 0; c < 4; ++c) {
        dma16(Ab + (size_t)c * 8 * 512 + k0n, AD + c * 8 * 64);
        dma16(Bb + (size_t)c * 8 * 512 + k0n, BD + c * 8 * 64);
      }
    }
    const u16* Ab_s = &As[buf][0];
    const u16* Bb_s = &Bs[buf][0];
    int ar0 = wm * 64 + nl, ar1 = wm * 64 + 32 + nl;
    int br0 = wn * 64 + nl, br1 = wn * 64 + 32 + nl;
    #pragma unroll
    for (int ks = 0; ks < 4; ++ks) {
      int sw = (((ks * 2 + h32) ^ (nl & 7)) << 3);
      bf16x8 fa0 = *(const bf16x8*)(Ab_s + ar0 * 64 + sw);
      bf16x8 fa1 = *(const bf16x8*)(Ab_s + ar1 * 64 + sw);
      bf16x8 fb0 = *(const bf16x8*)(Bb_s + br0 * 64 + sw);
      bf16x8 fb1 = *(const bf16x8*)(Bb_s + br1 * 64 + sw);
      a00 = __builtin_amdgcn_mfma_f32_32x32x16_bf16(fa0, fb0, a00, 0, 0, 0);
      a01 = __builtin_amdgcn_mfma_f32_32x32x16_bf16(fa0, fb1, a01, 0, 0, 0);
      a10 = __builtin_amdgcn_mfma_f32_32x32x16_bf16(fa1, fb0, a10, 0, 0, 0);
      a11 = __builtin_amdgcn_mfma_f32_32x32x16_bf16(fa1, fb1, a11, 0, 0, 0);
    }
    __syncthreads();
  }

  int nw = 1 << (lkshift - 6);
  #pragma unroll
  for (int am = 0; am < 2; ++am) {
    #pragma unroll
    for (int bn = 0; bn < 2; ++bn) {
      const f32x16* accp = am == 0 ? (bn == 0 ? &a00 : &a01)
                                   : (bn == 0 ? &a10 : &a11);
      f32x16 acc = *accp;
      int cn = n0 + wn * 64 + bn * 32 + nl;
      float bv = bf2f(bias[cn]);
      #pragma unroll
      for (int g = 0; g < 16; ++g) {
        int rm = m0 + wm * 64 + am * 32 + (g & 3) + 8 * (g >> 2) + 4 * h32;
        float v = acc[g] + bv;
        if (act) v = gelu_f(v);
        if (mode) {
          int bb = rm >> lkshift;
          int key = rm & ((1 << lkshift) - 1);
          int nt = key >> 6, kl = key & 63;
          int d = cn & 63;
          size_t ad = ((((size_t)bb * 8 + (cn >> 6)) * nw + nt) * 64 + kl) * 64
                      + (((d >> 3) ^ (kl & 7)) << 3) + (d & 7);
          C[ad] = f2bf(v);
        } else {
          size_t ad = (size_t)rm * 512 + cn;
          C[ad] = f2bf(v);
          if (out2) {
            if (f32o) ((float*)out2)[out2_off + ad] = v;
            else      ((u16*)out2)[out2_off + ad] = f2bf(v);
          }
        }
      }
    }
  }
}

// ---------------------------------------------------------------------------
// MFMA flash v13 (UNCHANGED): 4-wave shared K/V staging, mask-MFMA,
// triple-buffered DMA with counted vmcnt(8) across raw s_barrier.
// ---------------------------------------------------------------------------
__global__ __launch_bounds__(256, 4) void flash_mfma(
    const u16* __restrict__ Q,      // [B*Lq][512] row-major
    const u16* __restrict__ Kp,     // [bh:32][nt][kl:64][d-swizzled:64]
    const u16* __restrict__ VTp,    // [bh][nt][d:64][key-swizzled:64]
    const u16* __restrict__ IncA,   // mask tiles, batches < nbA
    const u16* __restrict__ IncB,   // mask tiles, batches >= nbA
    int nbA,
    void* __restrict__ Outv,
    u16* __restrict__ Opart, float* __restrict__ Lpart,
    int Lq, int Lk, int splits, int is_final, const u32* __restrict__ flag) {
  __shared__ u16 K_s[3][4096];
  __shared__ u16 V_s[3][4096];
  __shared__ u16 P_s[4][2048];

  int t = threadIdx.x;
  int wave = t >> 6, lane = t & 63;
  int nl = lane & 31, h32 = lane >> 5;
  int qtiles = Lq >> 7;              // 128-row q-tiles (4 waves x 32)
  int nwords = Lk >> 6;
  int chunk = (int)(gridDim.x >> 3);
  int wid = (blockIdx.x & 7) * chunk + (blockIdx.x >> 3);
  int r2 = wid % (qtiles * 32);
  int split = wid / (qtiles * 32);
  int qt = r2 % qtiles;
  int bh = r2 / qtiles;
  int h = bh & 7, b = bh >> 3;
  int row0 = qt * 128 + wave * 32;
  int per = nwords / splits;
  int tile0 = split * per;
  int f32o = is_final ? (int)(*flag) : 0;

  bf16x8 qf[4];
  {
    const u16* qp = Q + ((size_t)(b * Lq) + row0 + nl) * 512 + h * 64 + h32 * 8;
    #pragma unroll
    for (int ks = 0; ks < 4; ++ks) qf[ks] = *(const bf16x8*)(qp + ks * 16);
  }
  bf16x8 b0f = {}, b16f = {};
  #pragma unroll
  for (int e = 0; e < 8; ++e) {
    b0f[e]  = (nl == h32 * 8 + e)      ? (short)0x3F80 : (short)0;
    b16f[e] = (nl == 16 + h32 * 8 + e) ? (short)0x3F80 : (short)0;
  }

  const u16* Kbh = Kp + (size_t)bh * Lk * 64;
  const u16* Vbh = VTp + (size_t)bh * nwords * 4096;
  size_t tstr = (size_t)(Lq >> 5) * 2048;
  int qt2 = row0 >> 5;
  const u16* It = (b < nbA ? IncA + (size_t)b * 2097152
                           : IncB + (size_t)(b - nbA) * 2097152)
                  + (size_t)qt2 * 2048 + lane * 8;

  f32x16 o0 = {}, o1 = {};
  float lsum = 0.f;

  {
    const u16* TK = Kbh + (size_t)tile0 * 4096;
    const u16* TV = Vbh + (size_t)tile0 * 4096;
    #pragma unroll
    for (int c = 0; c < 2; ++c) {
      int ch = c * 4 + wave;
      dma16(TK + ch * 512 + lane * 8, &K_s[0][ch * 512]);
      dma16(TV + ch * 512 + lane * 8, &V_s[0][ch * 512]);
    }
    asm volatile("" ::: "memory");
    if (per > 1) {
      const u16* TK1 = TK + 4096;
      const u16* TV1 = TV + 4096;
      #pragma unroll
      for (int c = 0; c < 2; ++c) {
        int ch = c * 4 + wave;
        dma16(TK1 + ch * 512 + lane * 8, &K_s[1][ch * 512]);
        dma16(TV1 + ch * 512 + lane * 8, &V_s[1][ch * 512]);
      }
    }
    asm volatile("" ::: "memory");
  }
  bf16x8 mc0, mc1, mc2, mc3;
  {
    const u16* p = It + (size_t)tile0 * tstr;
    mc0 = *(const bf16x8*)(p);
    mc1 = *(const bf16x8*)(p + 512);
    mc2 = *(const bf16x8*)(p + 1024);
    mc3 = *(const bf16x8*)(p + 1536);
  }
  __syncthreads();

  for (int i = 0; i < per; ++i) {
    int nt = tile0 + i;
    int bi = i % 3;
    bf16x8 mn0, mn1, mn2, mn3;
    if (i + 2 < per) {
      int bd = (i + 2) % 3;
      const u16* TK = Kbh + (size_t)(nt + 2) * 4096;
      const u16* TV = Vbh + (size_t)(nt + 2) * 4096;
      #pragma unroll
      for (int c = 0; c < 2; ++c) {
        int ch = c * 4 + wave;
        dma16(TK + ch * 512 + lane * 8, &K_s[bd][ch * 512]);
        dma16(TV + ch * 512 + lane * 8, &V_s[bd][ch * 512]);
      }
    }
    asm volatile("" ::: "memory");
    if (i + 1 < per) {
      const u16* p = It + (size_t)(nt + 1) * tstr;
      mn0 = *(const bf16x8*)(p);
      mn1 = *(const bf16x8*)(p + 512);
      mn2 = *(const bf16x8*)(p + 1024);
      mn3 = *(const bf16x8*)(p + 1536);
    }

    f32x16 s0 = {}, s1 = {};
    #pragma unroll
    for (int ks = 0; ks < 4; ++ks) {
      int ch = ks * 2 + h32;
      bf16x8 k0 = *(const bf16x8*)&K_s[bi][nl * 64 + ((ch ^ (nl & 7)) << 3)];
      bf16x8 k1 = *(const bf16x8*)&K_s[bi][(32 + nl) * 64 + ((ch ^ (nl & 7)) << 3)];
      s0 = __builtin_amdgcn_mfma_f32_32x32x16_bf16(k0, qf[ks], s0, 0, 0, 0);
      s1 = __builtin_amdgcn_mfma_f32_32x32x16_bf16(k1, qf[ks], s1, 0, 0, 0);
    }
    s0 = __builtin_amdgcn_mfma_f32_32x32x16_bf16(mc0, b0f,  s0, 0, 0, 0);
    s0 = __builtin_amdgcn_mfma_f32_32x32x16_bf16(mc1, b16f, s0, 0, 0, 0);
    s1 = __builtin_amdgcn_mfma_f32_32x32x16_bf16(mc2, b0f,  s1, 0, 0, 0);
    s1 = __builtin_amdgcn_mfma_f32_32x32x16_bf16(mc3, b16f, s1, 0, 0, 0);

    #pragma unroll
    for (int gg = 0; gg < 4; ++gg) {
      float pv0[4], pv1[4];
      #pragma unroll
      for (int r = 0; r < 4; ++r) {
        int g = gg * 4 + r;
        float e0 = exp2f(fmaf(s0[g], SC2, -CS2));
        float e1 = exp2f(fmaf(s1[g], SC2, -CS2));
        pv0[r] = e0;
        pv1[r] = e1;
        lsum += e0 + e1;
      }
      uint2 a0, a1;
      a0.x = cvtpk(pv0[0], pv0[1]);
      a0.y = cvtpk(pv0[2], pv0[3]);
      a1.x = cvtpk(pv1[0], pv1[1]);
      a1.y = cvtpk(pv1[2], pv1[3]);
      *(uint2*)&P_s[wave][gg * 256 + nl * 8 + 4 * h32]       = a0;
      *(uint2*)&P_s[wave][(4 + gg) * 256 + nl * 8 + 4 * h32] = a1;
    }
    asm volatile("s_waitcnt lgkmcnt(0)" ::: "memory");
    #pragma unroll
    for (int ks2 = 0; ks2 < 4; ++ks2) {
      int ch = ks2 * 2 + h32;
      bf16x8 pf = *(const bf16x8*)&P_s[wave][ch * 256 + nl * 8];
      bf16x8 v0 = *(const bf16x8*)&V_s[bi][nl * 64 + ((ch ^ (nl & 7)) << 3)];
      bf16x8 v1 = *(const bf16x8*)&V_s[bi][(32 + nl) * 64 + ((ch ^ (nl & 7)) << 3)];
      o0 = __builtin_amdgcn_mfma_f32_32x32x16_bf16(pf, v0, o0, 0, 0, 0);
      o1 = __builtin_amdgcn_mfma_f32_32x32x16_bf16(pf, v1, o1, 0, 0, 0);
    }
    mc0 = mn0; mc1 = mn1; mc2 = mn2; mc3 = mn3;
    asm volatile("s_waitcnt vmcnt(8)" ::: "memory");
    __builtin_amdgcn_s_barrier();
  }
  lsum += __shfl_xor(lsum, 32);

  if (Opart) {
    u16* ob = Opart + (size_t)split * 2097152;
    #pragma unroll
    for (int g = 0; g < 16; ++g) {
      int m = (g & 3) + 8 * (g >> 2) + 4 * h32;
      size_t base = ((size_t)(b * Lq) + row0 + m) * 512 + h * 64;
      ob[base + nl]      = f2bf(o0[g]);
      ob[base + 32 + nl] = f2bf(o1[g]);
    }
    if (h32 == 0)
      Lpart[(size_t)split * 32768 + ((size_t)(b * Lq) + row0 + nl) * 8 + h] = lsum;
  } else {
    #pragma unroll
    for (int g = 0; g < 16; ++g) {
      int m = (g & 3) + 8 * (g >> 2) + 4 * h32;
      float lv = __shfl(lsum, m);
      float inv = 1.0f / (lv + 1e-30f);
      size_t base = ((size_t)(b * Lq) + row0 + m) * 512 + h * 64;
      float v0 = gelu_f(o0[g] * inv);
      float v1 = gelu_f(o1[g] * inv);
      if (f32o) {
        ((float*)Outv)[base + nl]      = v0;
        ((float*)Outv)[base + 32 + nl] = v1;
      } else {
        ((u16*)Outv)[base + nl]      = f2bf(v0);
        ((u16*)Outv)[base + 32 + nl] = f2bf(v1);
      }
    }
  }
}

// ---------------------------------------------------------------------------
// Fused: combine edge split-K partials + residual + LayerNorm (eps=1e-7)
// ---------------------------------------------------------------------------
__global__ __launch_bounds__(256) void ln_fused(const u16* __restrict__ Op,
                                                const float* __restrict__ Lp,
                                                const u16* __restrict__ E,
                                                const u16* __restrict__ g,
                                                const u16* __restrict__ bb,
                                                u16* __restrict__ out) {
  int r = blockIdx.x;
  int t = threadIdx.x;
  int e = t * 2;
  int h = e >> 6;
  float lv = Lp[r * 8 + h] + Lp[32768 + r * 8 + h] + 1e-30f;
  float inv = 1.0f / lv;
  size_t idx = (size_t)r * 512 + e;
  u32 u0 = *(const u32*)&Op[idx];
  u32 u1 = *(const u32*)&Op[2097152 + idx];
  u32 ue = *(const u32*)&E[idx];
  float x0 = bf2f((u16)(ue & 0xffffu)) +
             gelu_f((bf2f((u16)(u0 & 0xffffu)) + bf2f((u16)(u1 & 0xffffu))) * inv);
  float x1 = bf2f((u16)(ue >> 16)) +
             gelu_f((bf2f((u16)(u0 >> 16)) + bf2f((u16)(u1 >> 16))) * inv);
  float s = x0 + x1, q = x0 * x0 + x1 * x1;
  #pragma unroll
  for (int o = 32; o; o >>= 1) { s += __shfl_down(s, o); q += __shfl_down(q, o); }
  __shared__ float red[8];
  int wv = t >> 6, ln = t & 63;
  if (ln == 0) { red[wv] = s; red[4 + wv] = q; }
  __syncthreads();
  s = red[0] + red[1] + red[2] + red[3];
  q = red[4] + red[5] + red[6] + red[7];
  float mean = s * (1.f / 512.f);
  float var  = q * (1.f / 512.f) - mean * mean;
  float rs = rsqrtf(var + 1e-7f);
  u32 ug = *(const u32*)(g + e);
  u32 ub = *(const u32*)(bb + e);
  float y0 = (x0 - mean) * rs * bf2f((u16)(ug & 0xffffu)) + bf2f((u16)(ub & 0xffffu));
  float y1 = (x1 - mean) * rs * bf2f((u16)(ug >> 16)) + bf2f((u16)(ub >> 16));
  *(u32*)(out + idx) = (u32)f2bf(y0) | ((u32)f2bf(y1) << 16);
}

// ---------------------------------------------------------------------------
extern "C" void kernel_launch(void* const* d_in, const int* in_sizes, int n_in,
                              void* d_out, int out_size, void* d_ws, size_t ws_size,
                              hipStream_t stream) {
  (void)in_sizes; (void)n_in; (void)out_size;
  const int* inc = (const int*)d_in[1];

  char* ws = (char*)d_ws;
  u32* FLAG = (u32*)ws;
  u16* VEC  = (u16*)(ws + 1024);
  u16* WT   = (u16*)(ws + 65536);     // 4MB used; gap 4259840..8454144 free
  u16* XB   = (u16*)(ws + 8454144);   // X bf16; later Opart; later node tiles b0-2
  u16* EB   = (u16*)(ws + 16842752);  // E bf16; later node tiles (b0-2 tail)
  u16* QN   = (u16*)(ws + 21037056);  // row-major [8192][512]; KN/VN/QE contiguous
  u16* KN   = (u16*)(ws + 29425664);  // K' node; later ELN+H1
  u16* VN   = (u16*)(ws + 37814272);  // V' node; later KE/VE
  u16* QE   = (u16*)(ws + 46202880);  // later node tiles b3
  u16* EATT = (u16*)(ws + 50397184);  // edge tiles b0,b1 (w/ EFIN slot); later VTe
  u16* EFIN = (u16*)(ws + 54591488);
  const size_t NEEDED = 60882944;
  u16* ELN = (u16*)(ws + 29425664);
  u16* H1  = (u16*)(ws + 33619968);
  u16* KE  = (u16*)(ws + 37814272);
  u16* Opart = XB;                        // 2 x 4MB bf16 edge partials
  float* Lpart = (float*)(ws + 4259840);  // 256KB in WT gap
  u16* ETIL0 = EATT;                      // edge mask tiles b0,b1 (8MB)
  u16* ETIL1 = (u16*)d_out + 4194304;     // edge mask tiles b2,b3 (d_out+8MB;
                                          //  dead until EFIN/node-flash writes)
  u16* NTIL0 = XB;                        // node mask tiles b0-2 (12MB XB+EB)
  u16* NTIL1 = QE;                        // node mask tiles b3 (4MB)
  u16* VTn = (u16*)d_out;                 // 8MB
  u16* VTe = EATT;
  u16* VE  = (u16*)(ws + 42008576);

  detect_dtype<<<1, 64, 0, stream>>>((const u16*)d_in[0], FLAG);

  if (ws_size < NEEDED) {
    fill_diag<<<8192, 256, 0, stream>>>((u32*)d_out,
                                        1000.0f + (float)(ws_size >> 20), FLAG);
    return;
  }

  // ALL independent prep in one launch: convX | convE | wtrans | vec10 |
  // edge mask tiles
  prep_all<<<9217, 256, 0, stream>>>(
      d_in[0], d_in[3], inc,
      d_in[4], d_in[6], d_in[8], d_in[10], d_in[12], d_in[14], d_in[16], d_in[18],
      d_in[5], d_in[7], d_in[9], d_in[11], d_in[13], d_in[15], d_in[17], d_in[19],
      d_in[20], d_in[21],
      XB, EB, WT, VEC, ETIL0, ETIL1, FLAG);

  // X projections Q/K/V + E projection Q_e in ONE launch (mats 0..3):
  // blocks 768..895 -> mat 3 (A3=EB), C lands at QN+3*cStride == QE.
  gemm_tiled<<<896, 256, 0, stream>>>(XB, WT, 262144, VEC, 512,
                                      QN, 4194304, 0, 256, 0b0110u, 11,
                                      nullptr, 0, EB, FLAG);

  // V_n -> tile-blocked swizzled VT'
  transposeV<<<dim3(32, 32), 256, 0, stream>>>(VN, VTn, 2048);

  // edge attends nodes: split-K=2 partials
  flash_mfma<<<512, 256, 0, stream>>>(QE, KN, VTn, ETIL0, ETIL1, 2, nullptr,
                                      Opart, Lpart, 1024, 2048, 2, 0, FLAG);

  // fused combine + residual + LN -> ELN  (frees XB/EB/QE)
  ln_fused<<<4096, 256, 0, stream>>>(Opart, Lpart, EB,
                                     VEC + 8 * 512, VEC + 9 * 512, ELN);

  // node mask tiles (b0-2 -> XB+EB; b3 -> QE slot)
  inc_tiles_node<<<dim3(64, 16, 4), 256, 0, stream>>>(inc, NTIL0, NTIL1);

  gemm_tiled<<<128, 256, 0, stream>>>(ELN, WT + 6 * 262144, 0, VEC + 6 * 512, 0,
                                      H1, 0, 1, 128, 0, 11, nullptr, 0,
                                      nullptr, FLAG);
  // EFIN GEMM also writes E_ output (d_out chunk 2) dtype-aware
  gemm_tiled<<<128, 256, 0, stream>>>(H1, WT + 7 * 262144, 0, VEC + 7 * 512, 0,
                                      EFIN, 0, 0, 128, 0, 11,
                                      d_out, 4194304, nullptr, FLAG);

  // edge K/V from E_final (batched, both mode1, lkshift=10; KE/VE contiguous)
  gemm_tiled<<<256, 256, 0, stream>>>(EFIN, WT + 4 * 262144, 262144, VEC + 4 * 512, 512,
                                      KE, 2097152, 0, 128, 0b11u, 10,
                                      nullptr, 0, nullptr, FLAG);
  transposeV<<<dim3(16, 32), 256, 0, stream>>>(VE, VTe, 1024);

  // node attends edges -> X_ (final, dtype-aware)
  flash_mfma<<<512, 256, 0, stream>>>(QN, KE, VTe, NTIL0, NTIL1, 3, d_out,
                                      nullptr, nullptr, 2048, 1024, 1, 1, FLAG);
}